// Round 2
// baseline (386.095 us; speedup 1.0000x reference)
//
#include <hip/hip_runtime.h>
#include <cstdint>

#define B_   16
#define CIN  128
#define COUT 128
#define SD   512
#define H_   128
#define W_   128

typedef __bf16 bf16x8  __attribute__((ext_vector_type(8)));
typedef float  floatx4 __attribute__((ext_vector_type(4)));
typedef float floatx16 __attribute__((ext_vector_type(16)));

// ---------- kernel A: style[b][c] = (sv[b]/sqrt(512)) . proj_w[c] + proj_b[c]
__global__ void style_kernel(const float* __restrict__ sv, const float* __restrict__ pw,
                             const float* __restrict__ pb, float* __restrict__ style) {
    int bid = blockIdx.x;
    int b = bid >> 7, c = bid & 127;
    int lane = threadIdx.x;
    const float* svb = sv + b * SD;
    const float* pwc = pw + (size_t)c * SD;
    float s = 0.f;
#pragma unroll
    for (int i = 0; i < SD; i += 64) s += svb[i + lane] * pwc[i + lane];
#pragma unroll
    for (int off = 32; off > 0; off >>= 1) s += __shfl_down(s, off, 64);
    if (lane == 0) style[b * CIN + c] = s * 0.044194173824159216f + pb[c];
}

// ---------- kernel B: modulate + demod, emit bf16 in [b][tap][chunk][o][c16] layout
__global__ void modw_kernel(const float* __restrict__ weight, const float* __restrict__ style,
                            __bf16* __restrict__ wmod) {
    int bid = blockIdx.x;
    int b = bid >> 7, o = bid & 127;
    int c = threadIdx.x;  // 0..127
    float s = style[b * CIN + c];
    const float* wp = weight + ((size_t)o * CIN + c) * 9;
    float v[9];
    float ss = 0.f;
#pragma unroll
    for (int t = 0; t < 9; ++t) { v[t] = wp[t] * s; ss += v[t] * v[t]; }
#pragma unroll
    for (int off = 32; off > 0; off >>= 1) ss += __shfl_down(ss, off, 64);
    __shared__ float sh[2];
    int wid = c >> 6, lane = c & 63;
    if (lane == 0) sh[wid] = ss;
    __syncthreads();
    float d = rsqrtf(sh[0] + sh[1] + 1e-8f);
    int chunk = c >> 4, ci = c & 15;
#pragma unroll
    for (int t = 0; t < 9; ++t) {
        wmod[(((((size_t)b * 9 + t) * 8 + chunk) * 128 + o) * 16 + ci)] = (__bf16)(v[t] * d);
    }
}

// ---------- kernel C: fused transpose + implicit-GEMM conv
// block = o[0..127] x rows {h0,h0+1} x w[w0..w0+63]; 4 waves.
// Whole x-tile (4 rows x 66 wp x 128 c, bf16, ch-swizzled) staged ONCE into LDS
// directly from fp32 x (xpose kernel eliminated). Main loop: tap-outer, ch-inner,
// ZERO barriers: 72 iters of {1 ds_read_b128 + 4 prefetched A loads + 4 MFMA}.
// Each wave computes all 128 o for 1 row x 32 w (acc[4]); B-frag reuse = 4 MFMA/read.
//
// LDS layout (elem index): (row*66+wp)*128 + ((ch ^ (wp&7))*2 + hf)*8 + e
//   ch-XOR swizzle spreads the 32 lanes' b128 reads (wp = const+n) across all
//   8 4-bank groups uniformly (same balance as the previous kernel's pattern).
__global__ __launch_bounds__(256, 2)
void conv_kernel(const float* __restrict__ x, const __bf16* __restrict__ wmod,
                 float* __restrict__ out) {
    __shared__ __align__(16) __bf16 Xs[4 * 66 * 128];  // 67584 B -> 2 blocks/CU
    int w0 = blockIdx.x * 64;
    int h0 = blockIdx.y * 2;
    int b  = blockIdx.z;
    int tid = threadIdx.x;

    // ---- stage: thread = (c-pair p, input row). 17 vec loads + 66 b32 ds_writes.
    {
        int p = tid >> 2, row = tid & 3;
        int hh = h0 - 1 + row;
        bool rowok = (unsigned)hh < (unsigned)H_;
        const float* b0 = x + (((size_t)b * CIN + 2 * p) * H_ + (rowok ? hh : 0)) * W_;
        const float* b1 = b0 + H_ * W_;
        int ch = p >> 3, g = (p >> 2) & 1, ep = (p & 3) * 2;
        int robase = row * 66;
        // wp = 0 (w = w0-1) and wp = 65 (w = w0+64): scalar edges, zero if OOB
        {
            float v0 = 0.f, v1 = 0.f;
            if (rowok && w0 > 0) { v0 = b0[w0 - 1]; v1 = b1[w0 - 1]; }
            uint32_t pk = (uint32_t)__builtin_bit_cast(unsigned short, (__bf16)v0)
                        | ((uint32_t)__builtin_bit_cast(unsigned short, (__bf16)v1) << 16);
            int off = robase * 128 + ((ch ^ 0) * 2 + g) * 8 + ep;   // wp=0 -> wp&7=0
            *(uint32_t*)(Xs + off) = pk;
        }
        {
            float v0 = 0.f, v1 = 0.f;
            int w = w0 + 64;
            if (rowok && w < W_) { v0 = b0[w]; v1 = b1[w]; }
            uint32_t pk = (uint32_t)__builtin_bit_cast(unsigned short, (__bf16)v0)
                        | ((uint32_t)__builtin_bit_cast(unsigned short, (__bf16)v1) << 16);
            int off = (robase + 65) * 128 + ((ch ^ (65 & 7)) * 2 + g) * 8 + ep;
            *(uint32_t*)(Xs + off) = pk;
        }
        // interior wp = 1..64 from 16 aligned float4 per channel
#pragma unroll
        for (int j = 0; j < 16; ++j) {
            floatx4 va = {0.f, 0.f, 0.f, 0.f}, vb = {0.f, 0.f, 0.f, 0.f};
            if (rowok) {
                va = *(const floatx4*)(b0 + w0 + j * 4);
                vb = *(const floatx4*)(b1 + w0 + j * 4);
            }
#pragma unroll
            for (int k = 0; k < 4; ++k) {
                int wp = j * 4 + 1 + k;
                uint32_t pk = (uint32_t)__builtin_bit_cast(unsigned short, (__bf16)va[k])
                            | ((uint32_t)__builtin_bit_cast(unsigned short, (__bf16)vb[k]) << 16);
                int off = (robase + wp) * 128 + ((ch ^ (wp & 7)) * 2 + g) * 8 + ep;
                *(uint32_t*)(Xs + off) = pk;
            }
        }
    }
    __syncthreads();   // the ONLY barrier in the kernel

    // ---- compute
    int wv = tid >> 6, lane = tid & 63;
    int n = lane & 31, hf = lane >> 5;
    int r = wv & 1, whalf = wv >> 1;

    floatx16 acc[4];
#pragma unroll
    for (int i = 0; i < 4; ++i)
#pragma unroll
        for (int k = 0; k < 16; ++k) acc[i][k] = 0.f;

    // per-kw LDS address parts (runtime n; ch-XOR folded per unrolled iter)
    int wb[3], m2[3];
#pragma unroll
    for (int kw = 0; kw < 3; ++kw) {
        int wp = whalf * 32 + n + kw;
        wb[kw] = wp * 128 + hf * 8;
        m2[kw] = (wp & 7) * 2;
    }
    int roff = r * 8448;  // 66*128

    // A fragments: wmod elem = b*147456 + it*2048 + i*512 + n*16 + hf*8, it = tap*8+ch
    const __bf16* apb = wmod + (size_t)b * 147456 + n * 16 + hf * 8;

    bf16x8 ab[4][4];  // rotating prefetch slots; all indices compile-time post-unroll
#define LOADA(slot, it_)                                            \
    {                                                               \
        const __bf16* ap = apb + (it_) * 2048;                      \
        ab[slot][0] = *(const bf16x8*)(ap);                         \
        ab[slot][1] = *(const bf16x8*)(ap + 512);                   \
        ab[slot][2] = *(const bf16x8*)(ap + 1024);                  \
        ab[slot][3] = *(const bf16x8*)(ap + 1536);                  \
    }
    LOADA(0, 0) LOADA(1, 1) LOADA(2, 2)   // prefetch depth 3

#pragma unroll
    for (int tap = 0; tap < 9; ++tap) {
        const int kh = tap / 3, kw = tap % 3;
#pragma unroll
        for (int ch = 0; ch < 8; ++ch) {
            const int it = tap * 8 + ch;
            const bf16x8 bfrag = *(const bf16x8*)(
                &Xs[roff + kh * 8448 + wb[kw] + (((2 * ch) ^ m2[kw]) << 3)]);
            acc[0] = __builtin_amdgcn_mfma_f32_32x32x16_bf16(ab[it & 3][0], bfrag, acc[0], 0, 0, 0);
            acc[1] = __builtin_amdgcn_mfma_f32_32x32x16_bf16(ab[it & 3][1], bfrag, acc[1], 0, 0, 0);
            acc[2] = __builtin_amdgcn_mfma_f32_32x32x16_bf16(ab[it & 3][2], bfrag, acc[2], 0, 0, 0);
            acc[3] = __builtin_amdgcn_mfma_f32_32x32x16_bf16(ab[it & 3][3], bfrag, acc[3], 0, 0, 0);
            if (it + 3 < 72) LOADA((it + 3) & 3, it + 3)
        }
    }
#undef LOADA

    // epilogue: C/D layout col=lane&31, row=(reg&3)+8*(reg>>2)+4*(lane>>5)
    float* ob = out + (((size_t)b * COUT) * H_ + (h0 + r)) * W_ + w0 + whalf * 32;
#pragma unroll
    for (int i = 0; i < 4; ++i) {
#pragma unroll
        for (int reg = 0; reg < 16; ++reg) {
            int o = i * 32 + (reg & 3) + 8 * (reg >> 2) + 4 * hf;
            __builtin_nontemporal_store(acc[i][reg], &ob[(size_t)o * (H_ * W_) + n]);
        }
    }
}

extern "C" void kernel_launch(void* const* d_in, const int* in_sizes, int n_in,
                              void* d_out, int out_size, void* d_ws, size_t ws_size,
                              hipStream_t stream) {
    const float* x      = (const float*)d_in[0];
    const float* sv     = (const float*)d_in[1];
    const float* pw     = (const float*)d_in[2];
    const float* pb     = (const float*)d_in[3];
    const float* weight = (const float*)d_in[4];
    float* out = (float*)d_out;

    float*  style = (float*)d_ws;                            // 8 KB
    __bf16* wmod  = (__bf16*)((char*)d_ws + 8192);           // 4.72 MB

    style_kernel<<<B_ * CIN, 64, 0, stream>>>(sv, pw, pb, style);
    modw_kernel<<<B_ * COUT, 128, 0, stream>>>(weight, style, wmod);
    conv_kernel<<<dim3(2, 64, B_), 256, 0, stream>>>(x, wmod, out);
}